// Round 6
// baseline (306.765 us; speedup 1.0000x reference)
//
#include <hip/hip_runtime.h>

// Problem constants: B=8, C=4, H=W=512, K_ITERS=10, ALPHA=2
#define Wd  512
#define W4  128               // float4s per row
#define HWp 262144            // elements per (b,c) plane
#define BC  32                // B*C planes
#define NTOT 8388608
#define F_INF __int_as_float(0x7F800000)

// red layout (per-iteration slots, no reset needed):
//   red[k*96 + plane] = min, [k*96+32+plane] = max, [k*96+64+plane] = sum

__global__ void init_red_kernel(float* __restrict__ red)
{
    int i = blockIdx.x * 256 + threadIdx.x;
    if (i < 960) red[i] = ((i % 96) < 32) ? F_INF : 0.0f;
}

template <bool FIRST>
__global__ __launch_bounds__(256) void stencil_kernel(
    const float* __restrict__ in, float* __restrict__ out,
    const float* __restrict__ pred, const int* __restrict__ target,
    float* __restrict__ red, int k, int store)
{
    const int plane = blockIdx.y;
    const int chunk = blockIdx.x;        // 16 rows per block
    const int t     = threadIdx.x;
    const int col4  = t & 127;           // float4 column
    const int half  = t >> 7;            // 0..1 -> 8-row strip
    const int r0    = chunk * 16 + half * 8;
    const int b     = plane >> 2;
    const int c     = plane & 3;

    // per-plane affine from previous iteration's reduction (kernel boundary = sync)
    float s = 1.0f, o = 0.0f;
    if (!FIRST) {
        float mn = red[(k - 1) * 96 + plane];
        float mx = red[(k - 1) * 96 + 32 + plane];
        float dn = mx - mn;
        if (dn != 0.0f) { s = 1.0f / dn; o = -mn / dn; }
    }

    const float* ip = in + (size_t)plane * HWp;
    float*       op = out + (size_t)plane * HWp;
    const float* pp = pred + (size_t)plane * HWp;
    const int*   tp = target + (size_t)b * HWp;

    auto loadRow4 = [&](int grow) -> float4 {
        if (grow < 0 || grow > Wd - 1) return make_float4(0.f, 0.f, 0.f, 0.f);
        if constexpr (FIRST) {
            float4 pv = ((const float4*)pp)[grow * W4 + col4];
            int4   tv = ((const int4*)tp)[grow * W4 + col4];
            float dx = pv.x - (tv.x == c ? 1.0f : 0.0f);
            float dy = pv.y - (tv.y == c ? 1.0f : 0.0f);
            float dz = pv.z - (tv.z == c ? 1.0f : 0.0f);
            float dw = pv.w - (tv.w == c ? 1.0f : 0.0f);
            return make_float4(dx*dx, dy*dy, dz*dz, dw*dw);
        } else {
            return ((const float4*)ip)[grow * W4 + col4];
        }
    };
    auto load1 = [&](int grow, int x) -> float {
        if constexpr (FIRST) {
            float p = pp[grow * Wd + x];
            int   v = tp[grow * Wd + x];
            float d = p - (v == c ? 1.0f : 0.0f);
            return d * d;
        } else {
            return ip[grow * Wd + x];
        }
    };

    // preload the 10 rows this strip needs (independent loads, deep pipeline)
    float4 buf[10];
    #pragma unroll
    for (int i = 0; i < 10; ++i) buf[i] = loadRow4(r0 - 1 + i);

    const bool hasL = (col4 > 0);
    const bool hasR = (col4 < W4 - 1);
    float lmin = F_INF, lmax = 0.0f, lsum = 0.0f;

    #pragma unroll
    for (int i = 0; i < 8; ++i) {
        const int grow = r0 + i;
        float4 uu = buf[i], cc = buf[i + 1], dd = buf[i + 2];
        float lft = hasL ? load1(grow, 4 * col4 - 1) : 0.0f;  // L1-hot
        float rgt = hasR ? load1(grow, 4 * col4 + 4) : 0.0f;

        const float vc = (grow > 0 ? 1.0f : 0.0f) + (grow < Wd - 1 ? 1.0f : 0.0f);
        float4 sum, cnt;
        sum.x = cc.x + cc.y + uu.x + dd.x + lft;  cnt.x = 2.0f + (hasL ? 1.0f : 0.0f) + vc;
        sum.y = cc.x + cc.y + cc.z + uu.y + dd.y; cnt.y = 3.0f + vc;
        sum.z = cc.y + cc.z + cc.w + uu.z + dd.z; cnt.z = 3.0f + vc;
        sum.w = cc.z + cc.w + rgt + uu.w + dd.w;  cnt.w = 2.0f + (hasR ? 1.0f : 0.0f) + vc;

        float4 ev;
        ev.x = fmaxf(0.2f * (s * sum.x + o * cnt.x) - 0.5f, 0.0f);
        ev.y = fmaxf(0.2f * (s * sum.y + o * cnt.y) - 0.5f, 0.0f);
        ev.z = fmaxf(0.2f * (s * sum.z + o * cnt.z) - 0.5f, 0.0f);
        ev.w = fmaxf(0.2f * (s * sum.w + o * cnt.w) - 0.5f, 0.0f);

        if (store) ((float4*)op)[grow * W4 + col4] = ev;

        lmin = fminf(lmin, fminf(fminf(ev.x, ev.y), fminf(ev.z, ev.w)));
        lmax = fmaxf(lmax, fmaxf(fmaxf(ev.x, ev.y), fmaxf(ev.z, ev.w)));
        lsum += (ev.x + ev.y) + (ev.z + ev.w);
    }

    // wave (64) + block (4 waves) reduction
    for (int off = 32; off > 0; off >>= 1) {
        lmin = fminf(lmin, __shfl_down(lmin, off));
        lmax = fmaxf(lmax, __shfl_down(lmax, off));
        lsum += __shfl_down(lsum, off);
    }
    __shared__ float smin[4], smax[4], ssum[4];
    const int wave = t >> 6;
    if ((t & 63) == 0) { smin[wave] = lmin; smax[wave] = lmax; ssum[wave] = lsum; }
    __syncthreads();
    if (t == 0) {
        float bmin = smin[0], bmax = smax[0], bsum = ssum[0];
        for (int i = 1; i < 4; i++) {
            bmin = fminf(bmin, smin[i]);
            bmax = fmaxf(bmax, smax[i]);
            bsum += ssum[i];
        }
        // nonnegative floats: int compare == float compare
        atomicMin((int*)&red[k * 96 + plane],      __float_as_int(bmin));
        atomicMax((int*)&red[k * 96 + 32 + plane], __float_as_int(bmax));
        atomicAdd(&red[k * 96 + 64 + plane], bsum);
    }
}

// One block, 64 threads: closed-form contribution of every iteration
__global__ void final_kernel(const float* __restrict__ red, float* __restrict__ out)
{
    int t = threadIdx.x;
    float tot = 0.0f;
    #pragma unroll
    for (int k = 0; k < 10; ++k) {
        float cb = 0.0f;
        if (t < 32) {
            float mn = red[k * 96 + t];
            float mx = red[k * 96 + 32 + t];
            float sm = red[k * 96 + 64 + t];
            float dn = mx - mn;
            float ss, oo;
            if (dn != 0.0f) { ss = 1.0f / dn; oo = -mn / dn; }
            else            { ss = 1.0f;      oo = 0.0f; }
            float w = (float)((k + 1) * (k + 1));
            cb = (ss * sm + oo * 262144.0f) * w;  // sum of normalized plane
        }
        tot += cb;
    }
    for (int off = 32; off > 0; off >>= 1) tot += __shfl_down(tot, off);
    if (t == 0) out[0] = tot / 8388608.0f;
}

extern "C" void kernel_launch(void* const* d_in, const int* in_sizes, int n_in,
                              void* d_out, int out_size, void* d_ws, size_t ws_size,
                              hipStream_t stream)
{
    const float* pred = (const float*)d_in[0];
    const int* target = (const int*)d_in[1];
    float* out = (float*)d_out;

    float* buf0 = (float*)d_ws;
    float* buf1 = buf0 + NTOT;
    float* red  = buf1 + NTOT;   // 960 floats of per-iteration reduction state

    init_red_kernel<<<4, 256, 0, stream>>>(red);

    dim3 grid(32, BC);  // 32 row-chunks x 32 planes
    stencil_kernel<true><<<grid, 256, 0, stream>>>(nullptr, buf0, pred, target, red, 0, 1);

    float* a = buf0;
    float* b = buf1;
    for (int k = 1; k < 10; k++) {
        stencil_kernel<false><<<grid, 256, 0, stream>>>(a, b, pred, target, red, k, (k < 9) ? 1 : 0);
        float* tmp = a; a = b; b = tmp;
    }
    final_kernel<<<1, 64, 0, stream>>>(red, out);
}